// Round 6
// baseline (444.001 us; speedup 1.0000x reference)
//
#include <hip/hip_runtime.h>
#include <math.h>

#define BN_ 2
#define NN 1024
#define DDIM 256
#define HH 8
#define HDIM 32
#define FFD 1024
#define EPSV 1e-5f
#define SCALEV 0.17677669529663687f
#define LPAD 72

typedef __attribute__((ext_vector_type(8))) short s16x8;
typedef __attribute__((ext_vector_type(4))) float f32x4;

__device__ __forceinline__ float gelu_f(float x){
  return 0.5f*x*(1.0f+erff(x*0.70710678118654752f));
}
__device__ __forceinline__ unsigned int pack_bf16(float lo, float hi){
  unsigned int ul = __float_as_uint(lo), uh = __float_as_uint(hi);
  ul += 0x7fff + ((ul>>16)&1);
  uh += 0x7fff + ((uh>>16)&1);
  return (ul>>16) | (uh & 0xffff0000u);
}
__device__ __forceinline__ unsigned short f2bf(float x){
  unsigned int u = __float_as_uint(x);
  u += 0x7fff + ((u>>16)&1);
  return (unsigned short)(u>>16);
}
__device__ __forceinline__ float bf2f(unsigned short u){
  return __uint_as_float(((unsigned int)u)<<16);
}
__device__ __forceinline__ f32x4 mfma16(s16x8 a, s16x8 b, f32x4 c){
  return __builtin_amdgcn_mfma_f32_16x16x32_bf16(a,b,c,0,0,0);
}

// ---------------- LayerNorm: f32 in, bf16 out --------------------------------
__global__ __launch_bounds__(256) void ln_kernel(const float* __restrict__ x,
    const float* __restrict__ g, const float* __restrict__ b,
    unsigned short* __restrict__ out){
  int row = blockIdx.x, tid = threadIdx.x;
  float val = x[(size_t)row*DDIM + tid];
  float s = val;
  #pragma unroll
  for (int o=32;o;o>>=1) s += __shfl_xor(s,o);
  __shared__ float sb[4], sb2[4];
  if ((tid&63)==0) sb[tid>>6]=s;
  __syncthreads();
  float mean = (sb[0]+sb[1]+sb[2]+sb[3]) * (1.0f/DDIM);
  float d = val-mean;
  float vs = d*d;
  #pragma unroll
  for (int o=32;o;o>>=1) vs += __shfl_xor(vs,o);
  if ((tid&63)==0) sb2[tid>>6]=vs;
  __syncthreads();
  float var = (sb2[0]+sb2[1]+sb2[2]+sb2[3]) * (1.0f/DDIM);
  out[(size_t)row*DDIM + tid] = f2bf(d*rsqrtf(var+EPSV)*g[tid]+b[tid]);
}

// ---------------- RoPE tables -------------------------------------------------
__global__ __launch_bounds__(256) void rope_table(float* __restrict__ sint, float* __restrict__ cost){
  int idx = blockIdx.x*256+threadIdx.x;   // 16384
  int i = idx >> 4, d = idx & 15;
  float freq = (float)i * powf(10000.0f, -(float)d/16.0f);
  sint[idx]=sinf(freq); cost[idx]=cosf(freq);
}

// ---------------- weight convert+transpose f32(K,NC) -> bf16 WT(NC,K) --------
__global__ __launch_bounds__(256) void wt_convert(const float* __restrict__ in,
    unsigned short* __restrict__ out, int K, int NC, int scaleCols, float scaleVal){
  __shared__ float tile[32][33];
  int tn0 = blockIdx.x*32;
  int tk0 = blockIdx.y*32;
  size_t loff = (size_t)blockIdx.z * K * NC;
  int t = threadIdx.x;
  int col = t & 31, rr = t >> 5;
  #pragma unroll
  for (int i=0;i<4;++i){
    int row = rr + i*8;
    tile[row][col] = in[loff + (size_t)(tk0+row)*NC + tn0+col];
  }
  __syncthreads();
  #pragma unroll
  for (int i=0;i<4;++i){
    int row = rr + i*8;
    int n = tn0 + row;
    float s = (n < scaleCols) ? scaleVal : 1.0f;
    out[loff + (size_t)n*K + tk0 + col] = f2bf(tile[col][row]*s);
  }
}

// ------------- split qkv + rope (bf16 in/out) --------------------------------
__global__ __launch_bounds__(256) void rope_apply_bf(const unsigned short* __restrict__ qkv,
    const float* __restrict__ sint, const float* __restrict__ cost,
    unsigned short* __restrict__ q, unsigned short* __restrict__ k,
    unsigned short* __restrict__ v){
  int row = blockIdx.x;                 // b*1024 + i
  int b = row>>10, i = row&1023;
  int tid = threadIdx.x; int h = tid>>5, d = tid&31;
  const unsigned short* base = qkv + (size_t)row*768;
  size_t oidx = (((size_t)((b<<3)+h)<<10) + i)*32 + d;
  v[oidx] = base[512 + h*32 + d];
  int dd = (d<16) ? d : d-16;
  float s = sint[i*16+dd], c = cost[i*16+dd];
  float q1 = bf2f(base[h*32+dd]), q2 = bf2f(base[h*32+dd+16]);
  q[oidx] = f2bf((d<16) ? (q1*c - q2*s) : (q2*c + q1*s));
  float k1 = bf2f(base[256+h*32+dd]), k2 = bf2f(base[256+h*32+dd+16]);
  k[oidx] = f2bf((d<16) ? (k1*c - k2*s) : (k2*c + k1*s));
}

// ------------- rel precompute: per-node separable parts + W2T ----------------
// blocks 0..511: A[node][64], BT[r][2048].  block 512: W2T[16][64] bf16 (n<8 valid)
__global__ __launch_bounds__(256) void rel_pre(const float* __restrict__ coords,
    const float* __restrict__ vel, const float* __restrict__ W1,
    const float* __restrict__ b1, const float* __restrict__ W2,
    float* __restrict__ A, float* __restrict__ BT, unsigned short* __restrict__ W2T){
  if (blockIdx.x == 512){
    int t = threadIdx.x;
    #pragma unroll
    for (int e=0;e<4;++e){
      int idx = t*4+e;              // n*64 + k
      int n = idx>>6, kk = idx&63;
      W2T[idx] = (n<8) ? f2bf(W2[kk*8+n]) : 0;
    }
    return;
  }
  int gid = blockIdx.x*256 + threadIdx.x;  // 2048*64
  int node = gid >> 6, r = gid & 63;
  float c0 = coords[node*2], c1 = coords[node*2+1];
  float v0 = vel[node*2],    v1 = vel[node*2+1];
  float bv = c0*W1[r] + c1*W1[64+r] + v0*W1[192+r] + v1*W1[256+r];
  A[gid] = b1[r] + bv;
  BT[r*2048 + node] = bv;
}

// ------------- rel fused: block = (b,i); gelu-poly + MFMA W2 -----------------
// t[r](i,j) = A_i[r] - B_j[r] + dist(i,j)*Wd[r]; G=gelu(t) bf16 in LDS;
// rel[b,h,i,j] = (G @ W2)[j][h] + b2[h], stored packed-bf16.
__global__ __launch_bounds__(256) void rel_fused(const float* __restrict__ coords,
    const float* __restrict__ A, const float* __restrict__ BT,
    const float* __restrict__ W1, const unsigned short* __restrict__ W2T,
    const float* __restrict__ b2, unsigned int* __restrict__ relbf){
  __shared__ __align__(16) unsigned short G[256*72];
  __shared__ __align__(16) float Tld[8][260];
  const int tid = threadIdx.x;
  const int nodei = blockIdx.x;
  const int b = nodei >> 10, i = nodei & 1023;
  const int w = tid>>6, l = tid&63, lc = l&15, lg = l>>4;
  const float* Ai = A + (size_t)nodei*64;
  const float* Wd = W1 + 128;
  float ci0 = coords[nodei*2], ci1 = coords[nodei*2+1];
  // B-fragment of W2 (uniform across tiles): lane(n=lc, k=lg*8+e [+32])
  s16x8 bf0 = *(const s16x8*)&W2T[lc*64 + lg*8];
  s16x8 bf1 = *(const s16x8*)&W2T[lc*64 + 32 + lg*8];
  float b2v = (lc<8) ? b2[lc] : 0.f;
  unsigned int obase = ((unsigned)b<<22) + ((unsigned)i<<9);

  for (int jt=0; jt<4; ++jt){
    // ---- Phase A: per-thread j, compute 64 gelu(t) -> G (swizzled slots) ----
    {
      int j = jt*256 + tid;
      int nodej = (b<<10) + j;
      float2 cj = *(const float2*)(coords + (size_t)nodej*2);
      float dx = ci0-cj.x, dy = ci1-cj.y;
      float d = sqrtf(dx*dx+dy*dy);
      const float* bt = BT + nodej;
      int gw = tid*72;
      int sw = 2*(tid&7);
      #pragma unroll
      for (int rg=0; rg<8; ++rg){
        s16x8 pk;
        #pragma unroll
        for (int e=0; e<8; ++e){
          int r = rg*8+e;
          float t = fmaf(d, Wd[r], Ai[r] - bt[(size_t)r*2048]);
          float u = t*t;
          float p = fmaf(u, 0.0099735570f, -0.0664904395f);
          p = fmaf(u, p, 0.3989422804f);
          float g = fmaf(u, p, 0.5f*t);
          pk[e] = (short)f2bf(g);
        }
        *(s16x8*)&G[gw + (((rg + sw)&7)<<3)] = pk;
      }
    }
    __syncthreads();
    // ---- Phase B: MFMA G @ W2T, write Tld[h][j] ----
    f32x4 acc[4];
    #pragma unroll
    for (int a=0;a<4;++a){
      int row = w*64 + a*16 + lc;
      int rb = row*72;
      int r7 = 2*(row&7);
      s16x8 a0 = *(const s16x8*)&G[rb + (((lg + r7)&7)<<3)];
      s16x8 a1 = *(const s16x8*)&G[rb + (((4 + lg + r7)&7)<<3)];
      f32x4 z; z[0]=0.f; z[1]=0.f; z[2]=0.f; z[3]=0.f;
      z = mfma16(a0, bf0, z);
      acc[a] = mfma16(a1, bf1, z);
    }
    if (lc < 8){
      #pragma unroll
      for (int a=0;a<4;++a){
        int jr = w*64 + a*16 + lg*4;
        Tld[lc][jr+0] = acc[a][0]+b2v;
        Tld[lc][jr+1] = acc[a][1]+b2v;
        Tld[lc][jr+2] = acc[a][2]+b2v;
        Tld[lc][jr+3] = acc[a][3]+b2v;
      }
    }
    __syncthreads();
    // ---- Phase C: pack + coalesced store ----
    {
      int hh = tid>>5, jj = tid&31;
      const float4* tr = (const float4*)&Tld[hh][jj*8];
      float4 vA = tr[0], vB = tr[1];
      uint4 o;
      o.x = pack_bf16(vA.x, vA.y); o.y = pack_bf16(vA.z, vA.w);
      o.z = pack_bf16(vB.x, vB.y); o.w = pack_bf16(vB.z, vB.w);
      *(uint4*)&relbf[obase + ((unsigned)hh<<19) + jt*128 + jj*4] = o;
    }
  }
}

// ------------- MFMA flash attention (all-bf16 inputs) -------------------------
__global__ __launch_bounds__(256) void attn_mfma(
    const unsigned short* __restrict__ q, const unsigned short* __restrict__ kk,
    const unsigned short* __restrict__ vv, const unsigned short* __restrict__ relbf,
    unsigned short* __restrict__ out){
  int bh = blockIdx.x >> 5;
  int i0 = (blockIdx.x & 31) * 32;
  int tid = threadIdx.x;
  int w  = tid >> 6;
  int l  = tid & 63;
  int lc = l & 15;
  int lg = l >> 4;

  __shared__ __align__(16) unsigned short VT[2][32*LPAD];
  __shared__ __align__(16) unsigned short PL[2][32*LPAD];
  __shared__ __align__(16) float wmaxs[2][32][4];
  __shared__ __align__(16) float wsums[2][32][4];
  __shared__ float mld[2][32];
  __shared__ float lld[2][32];

  const unsigned short* qb = q + ((size_t)(bh<<10) + i0)*32;
  const unsigned short* kb = kk + ((size_t)bh<<15);
  const unsigned short* vb = vv + ((size_t)bh<<15);
  const unsigned short* relb = relbf + ((size_t)bh<<20) + ((size_t)i0<<10);

  s16x8 qf0 = *(const s16x8*)(qb + (size_t)lc*32 + lg*8);
  s16x8 qf1 = *(const s16x8*)(qb + (size_t)(16+lc)*32 + lg*8);

  if (tid < 32){ mld[0][tid] = -1e30f; lld[0][tid] = 0.f; }

  f32x4 acc; acc[0]=0.f; acc[1]=0.f; acc[2]=0.f; acc[3]=0.f;
  const int dh  = w & 1;
  const int pih = w >> 1;

  for (int t=0; t<16; ++t){
    const int c = t & 1, nx = c ^ 1;
    const int j0 = t*64;
    {
      int jj = tid & 63, d0 = (tid >> 6)*8;
      s16x8 v8 = *(const s16x8*)(vb + (size_t)(j0+jj)*32 + d0);
      unsigned short* dst = VT[c];
      #pragma unroll
      for (int e=0;e<8;++e) dst[(d0+e)*LPAD + jj] = (unsigned short)v8[e];
    }
    s16x8 kf = *(const s16x8*)(kb + (size_t)(j0 + w*16 + lc)*32 + lg*8);
    f32x4 z; z[0]=0.f; z[1]=0.f; z[2]=0.f; z[3]=0.f;
    f32x4 s0 = mfma16(qf0, kf, z);
    f32x4 s1 = mfma16(qf1, kf, z);
    float sv0[4], sv1[4], rm0[4], rm1[4];
    const int jc = j0 + w*16 + lc;
    #pragma unroll
    for (int r=0;r<4;++r){
      int row0 = lg*4 + r;
      sv0[r] = s0[r] + bf2f(relb[(size_t)row0*1024 + jc]);
      sv1[r] = s1[r] + bf2f(relb[(size_t)(row0+16)*1024 + jc]);
      float a0 = sv0[r], a1 = sv1[r];
      #pragma unroll
      for (int o=1;o<16;o<<=1){
        a0 = fmaxf(a0, __shfl_xor(a0,o));
        a1 = fmaxf(a1, __shfl_xor(a1,o));
      }
      rm0[r]=a0; rm1[r]=a1;
    }
    if (lc == 0){
      #pragma unroll
      for (int r=0;r<4;++r){
        wmaxs[c][lg*4+r][w]    = rm0[r];
        wmaxs[c][lg*4+r+16][w] = rm1[r];
      }
    }
    __syncthreads();
    float mn0[4], mn1[4], sc0[4], sc1[4];
    #pragma unroll
    for (int r=0;r<4;++r){
      int row0 = lg*4+r;
      float4 wm0 = *(const float4*)wmaxs[c][row0];
      float4 wm1 = *(const float4*)wmaxs[c][row0+16];
      float mo0 = mld[c][row0], mo1 = mld[c][row0+16];
      float t0 = fmaxf(fmaxf(wm0.x,wm0.y), fmaxf(wm0.z,wm0.w));
      float t1 = fmaxf(fmaxf(wm1.x,wm1.y), fmaxf(wm1.z,wm1.w));
      mn0[r] = fmaxf(mo0, t0);  mn1[r] = fmaxf(mo1, t1);
      sc0[r] = __expf(mo0 - mn0[r]); sc1[r] = __expf(mo1 - mn1[r]);
    }
    float ps0[4], ps1[4];
    #pragma unroll
    for (int r=0;r<4;++r){
      int row0 = lg*4+r;
      float p0 = __expf(sv0[r]-mn0[r]);
      float p1 = __expf(sv1[r]-mn1[r]);
      PL[c][(size_t)row0*LPAD + w*16 + lc]      = f2bf(p0);
      PL[c][(size_t)(row0+16)*LPAD + w*16 + lc] = f2bf(p1);
      #pragma unroll
      for (int o=1;o<16;o<<=1){
        p0 += __shfl_xor(p0,o);
        p1 += __shfl_xor(p1,o);
      }
      ps0[r]=p0; ps1[r]=p1;
    }
    if (lc == 0){
      #pragma unroll
      for (int r=0;r<4;++r){
        wsums[c][lg*4+r][w]    = ps0[r];
        wsums[c][lg*4+r+16][w] = ps1[r];
      }
    }
    #pragma unroll
    for (int r=0;r<4;++r){
      float s = (pih==0) ? sc0[r] : sc1[r];
      acc[r] *= s;
    }
    __syncthreads();
    #pragma unroll
    for (int kc=0;kc<2;++kc){
      s16x8 pa = *(const s16x8*)&PL[c][(size_t)(pih*16 + lc)*LPAD + kc*32 + lg*8];
      s16x8 vf = *(const s16x8*)&VT[c][(size_t)(dh*16 + lc)*LPAD + kc*32 + lg*8];
      acc = mfma16(pa, vf, acc);
    }
    if (w==0 && lc==0){
      #pragma unroll
      for (int r=0;r<4;++r){
        int row0 = lg*4+r;
        float4 u0 = *(const float4*)wsums[c][row0];
        float4 u1 = *(const float4*)wsums[c][row0+16];
        lld[nx][row0]    = lld[c][row0]*sc0[r]    + (u0.x+u0.y+u0.z+u0.w);
        lld[nx][row0+16] = lld[c][row0+16]*sc1[r] + (u1.x+u1.y+u1.z+u1.w);
        mld[nx][row0]    = mn0[r];
        mld[nx][row0+16] = mn1[r];
      }
    }
  }
  __syncthreads();
  int b = bh>>3, hh = bh&7;
  #pragma unroll
  for (int r=0;r<4;++r){
    int row = pih*16 + lg*4 + r;
    float li = lld[0][row];
    out[((size_t)((b<<10)+i0+row))*256 + hh*32 + dh*16 + lc] = f2bf(acc[r]/li);
  }
}

// ------------- MFMA GEMM: C[M,NC] = A[M,K] @ W[K,NC], A bf16, WT bf16(NC,K) --
template<int K, int NC, int EPI, int BM, int BNt>
__global__ __launch_bounds__(256) void gemm_mfma(
    const unsigned short* __restrict__ Aa, const unsigned short* __restrict__ WT,
    const float* __restrict__ bias, const float* __restrict__ resid,
    void* __restrict__ outv){
  constexpr int WMm = BM/2, WNn = BNt/2;
  constexpr int FM = WMm/16, FN = WNn/16;
  constexpr int LP = 40;
  __shared__ __align__(16) unsigned short As[BM*LP];
  __shared__ __align__(16) unsigned short Bs[BNt*LP];
  const int tid = threadIdx.x;
  const int w = tid>>6, l = tid&63, lc = l&15, lg = l>>4;
  const int wm = w&1, wn = w>>1;
  const int n0 = blockIdx.x*BNt, m0 = blockIdx.y*BM;
  f32x4 acc[FM][FN];
  #pragma unroll
  for (int a=0;a<FM;++a)
    #pragma unroll
    for (int c=0;c<FN;++c){ acc[a][c][0]=0.f; acc[a][c][1]=0.f; acc[a][c][2]=0.f; acc[a][c][3]=0.f; }

  for (int k0=0; k0<K; k0+=32){
    __syncthreads();
    if constexpr (BM==64){
      int row = tid>>2, cg = tid&3;
      *(s16x8*)&As[row*LP+cg*8] = *(const s16x8*)&Aa[(size_t)(m0+row)*K + k0 + cg*8];
    } else {
      int row = tid>>3, cg = tid&7;
      *(ushort4*)&As[row*LP+cg*4] = *(const ushort4*)&Aa[(size_t)(m0+row)*K + k0 + cg*4];
    }
    if constexpr (BNt==64){
      int row = tid>>2, cg = tid&3;
      *(s16x8*)&Bs[row*LP+cg*8] = *(const s16x8*)&WT[(size_t)(n0+row)*K + k0 + cg*8];
    } else {
      int row = tid>>3, cg = tid&7;
      *(ushort4*)&Bs[row*LP+cg*4] = *(const ushort4*)&WT[(size_t)(n0+row)*K + k0 + cg*4];
    }
    __syncthreads();
    s16x8 af[FM], bv[FN];
    #pragma unroll
    for (int a=0;a<FM;++a) af[a] = *(const s16x8*)&As[(wm*WMm + a*16 + lc)*LP + lg*8];
    #pragma unroll
    for (int c=0;c<FN;++c) bv[c] = *(const s16x8*)&Bs[(wn*WNn + c*16 + lc)*LP + lg*8];
    #pragma unroll
    for (int a=0;a<FM;++a)
      #pragma unroll
      for (int c=0;c<FN;++c) acc[a][c] = mfma16(af[a], bv[c], acc[a][c]);
  }
  #pragma unroll
  for (int a=0;a<FM;++a){
    #pragma unroll
    for (int c=0;c<FN;++c){
      int n = n0 + wn*WNn + c*16 + lc;
      float bvv = (EPI!=0) ? bias[n] : 0.f;
      #pragma unroll
      for (int r=0;r<4;++r){
        int m = m0 + wm*WMm + a*16 + lg*4 + r;
        float vv = acc[a][c][r];
        if constexpr (EPI==0){
          ((unsigned short*)outv)[(size_t)m*NC + n] = f2bf(vv);
        } else if constexpr (EPI==1){
          ((float*)outv)[(size_t)m*NC + n] = vv + bvv + resid[(size_t)m*NC + n];
        } else {
          ((unsigned short*)outv)[(size_t)m*NC + n] = f2bf(gelu_f(vv + bvv));
        }
      }
    }
  }
}

extern "C" void kernel_launch(void* const* d_in, const int* in_sizes, int n_in,
                              void* d_out, int out_size, void* d_ws, size_t ws_size,
                              hipStream_t stream){
  const float* x_in  = (const float*)d_in[0];
  const float* coords= (const float*)d_in[1];
  const float* vel   = (const float*)d_in[2];
  const float* ln1_g = (const float*)d_in[3];
  const float* ln1_b = (const float*)d_in[4];
  const float* Wqkv  = (const float*)d_in[5];
  const float* relW1 = (const float*)d_in[6];
  const float* relb1 = (const float*)d_in[7];
  const float* relW2 = (const float*)d_in[8];
  const float* relb2 = (const float*)d_in[9];
  const float* Wout  = (const float*)d_in[10];
  const float* bout  = (const float*)d_in[11];
  const float* ln2_g = (const float*)d_in[12];
  const float* ln2_b = (const float*)d_in[13];
  const float* Wf1   = (const float*)d_in[14];
  const float* bf1   = (const float*)d_in[15];
  const float* Wf2   = (const float*)d_in[16];
  const float* bf2   = (const float*)d_in[17];

  float* x = (float*)d_out;
  unsigned short* us = (unsigned short*)d_ws;
  unsigned short* hbf   = us;                    // 524288
  unsigned short* qkvbf = hbf   + 524288;        // 1572864
  unsigned short* qbf   = qkvbf + 1572864;       // 524288
  unsigned short* kbf   = qbf   + 524288;        // 524288
  unsigned short* vbf   = kbf   + 524288;        // 524288
  unsigned short* attbf = vbf   + 524288;        // 524288
  unsigned short* midbf = attbf + 524288;        // 2097152
  unsigned short* relbf = midbf + 2097152;       // 16777216
  unsigned short* WqkvT = relbf + 16777216;      // 393216
  unsigned short* WoutT = WqkvT + 393216;        // 131072
  unsigned short* Wf1T  = WoutT + 131072;        // 524288
  unsigned short* Wf2T  = Wf1T  + 524288;        // 524288
  unsigned short* W2Tbf = Wf2T  + 524288;        // 1024
  float* Arel = (float*)(W2Tbf + 1024);          // 131072
  float* BTrel= Arel + 131072;                   // 131072
  float* sint = BTrel + 131072;                  // 16384
  float* cost = sint + 16384;                    // 16384

  hipMemcpyAsync(x, x_in, sizeof(float)*524288, hipMemcpyDeviceToDevice, stream);
  rope_table<<<64,256,0,stream>>>(sint,cost);
  wt_convert<<<dim3(24,8,2),256,0,stream>>>(Wqkv, WqkvT, 256, 768, 256, SCALEV);
  wt_convert<<<dim3(8,8,2),256,0,stream>>>(Wout, WoutT, 256, 256, 0, 1.0f);
  wt_convert<<<dim3(32,8,2),256,0,stream>>>(Wf1, Wf1T, 256, 1024, 0, 1.0f);
  wt_convert<<<dim3(8,32,2),256,0,stream>>>(Wf2, Wf2T, 1024, 256, 0, 1.0f);

  for (int l=0;l<2;++l){
    ln_kernel<<<2048,256,0,stream>>>(x, ln1_g+l*256, ln1_b+l*256, hbf);
    gemm_mfma<256,768,0,64,64><<<dim3(12,32),256,0,stream>>>(
        hbf, WqkvT + (size_t)l*196608, nullptr, nullptr, qkvbf);
    rope_apply_bf<<<2048,256,0,stream>>>(qkvbf, sint, cost, qbf, kbf, vbf);
    rel_pre<<<513,256,0,stream>>>(coords, vel, relW1+l*320, relb1+l*64,
                                  relW2+l*512, Arel, BTrel, W2Tbf);
    rel_fused<<<2048,256,0,stream>>>(coords, Arel, BTrel, relW1+l*320,
                                     W2Tbf, relb2+l*8, (unsigned int*)relbf);
    attn_mfma<<<512,256,0,stream>>>(qbf, kbf, vbf, relbf, attbf);
    gemm_mfma<256,256,1,64,32><<<dim3(8,32),256,0,stream>>>(
        attbf, WoutT + (size_t)l*65536, bout+l*256, x, x);
    ln_kernel<<<2048,256,0,stream>>>(x, ln2_g+l*256, ln2_b+l*256, hbf);
    gemm_mfma<256,1024,2,64,64><<<dim3(16,32),256,0,stream>>>(
        hbf, Wf1T + (size_t)l*262144, bf1+l*1024, nullptr, midbf);
    gemm_mfma<1024,256,1,64,32><<<dim3(8,32),256,0,stream>>>(
        midbf, Wf2T + (size_t)l*262144, bf2+l*256, x, x);
  }
}

// Round 7
// 330.164 us; speedup vs baseline: 1.3448x; 1.3448x over previous
//
#include <hip/hip_runtime.h>
#include <math.h>

#define BN_ 2
#define NN 1024
#define DDIM 256
#define HH 8
#define HDIM 32
#define FFD 1024
#define EPSV 1e-5f
#define SCALEV 0.17677669529663687f
#define LPAD 72

typedef __attribute__((ext_vector_type(8))) short s16x8;
typedef __attribute__((ext_vector_type(4))) float f32x4;

__device__ __forceinline__ float gelu_f(float x){
  return 0.5f*x*(1.0f+erff(x*0.70710678118654752f));
}
__device__ __forceinline__ unsigned int pack_bf16(float lo, float hi){
  unsigned int ul = __float_as_uint(lo), uh = __float_as_uint(hi);
  ul += 0x7fff + ((ul>>16)&1);
  uh += 0x7fff + ((uh>>16)&1);
  return (ul>>16) | (uh & 0xffff0000u);
}
__device__ __forceinline__ unsigned short f2bf(float x){
  unsigned int u = __float_as_uint(x);
  u += 0x7fff + ((u>>16)&1);
  return (unsigned short)(u>>16);
}
__device__ __forceinline__ float bf2f(unsigned short u){
  return __uint_as_float(((unsigned int)u)<<16);
}
__device__ __forceinline__ f32x4 mfma16(s16x8 a, s16x8 b, f32x4 c){
  return __builtin_amdgcn_mfma_f32_16x16x32_bf16(a,b,c,0,0,0);
}

// ---------------- LayerNorm: f32 in, bf16 out --------------------------------
__global__ __launch_bounds__(256) void ln_kernel(const float* __restrict__ x,
    const float* __restrict__ g, const float* __restrict__ b,
    unsigned short* __restrict__ out){
  int row = blockIdx.x, tid = threadIdx.x;
  float val = x[(size_t)row*DDIM + tid];
  float s = val;
  #pragma unroll
  for (int o=32;o;o>>=1) s += __shfl_xor(s,o);
  __shared__ float sb[4], sb2[4];
  if ((tid&63)==0) sb[tid>>6]=s;
  __syncthreads();
  float mean = (sb[0]+sb[1]+sb[2]+sb[3]) * (1.0f/DDIM);
  float d = val-mean;
  float vs = d*d;
  #pragma unroll
  for (int o=32;o;o>>=1) vs += __shfl_xor(vs,o);
  if ((tid&63)==0) sb2[tid>>6]=vs;
  __syncthreads();
  float var = (sb2[0]+sb2[1]+sb2[2]+sb2[3]) * (1.0f/DDIM);
  out[(size_t)row*DDIM + tid] = f2bf(d*rsqrtf(var+EPSV)*g[tid]+b[tid]);
}

// ---------------- RoPE tables -------------------------------------------------
__global__ __launch_bounds__(256) void rope_table(float* __restrict__ sint, float* __restrict__ cost){
  int idx = blockIdx.x*256+threadIdx.x;   // 16384
  int i = idx >> 4, d = idx & 15;
  float freq = (float)i * powf(10000.0f, -(float)d/16.0f);
  sint[idx]=sinf(freq); cost[idx]=cosf(freq);
}

// ---------------- weight convert+transpose f32(K,NC) -> bf16 WT(NC,K) --------
__global__ __launch_bounds__(256) void wt_convert(const float* __restrict__ in,
    unsigned short* __restrict__ out, int K, int NC, int scaleCols, float scaleVal){
  __shared__ float tile[32][33];
  int tn0 = blockIdx.x*32;
  int tk0 = blockIdx.y*32;
  size_t loff = (size_t)blockIdx.z * K * NC;
  int t = threadIdx.x;
  int col = t & 31, rr = t >> 5;
  #pragma unroll
  for (int i=0;i<4;++i){
    int row = rr + i*8;
    tile[row][col] = in[loff + (size_t)(tk0+row)*NC + tn0+col];
  }
  __syncthreads();
  #pragma unroll
  for (int i=0;i<4;++i){
    int row = rr + i*8;
    int n = tn0 + row;
    float s = (n < scaleCols) ? scaleVal : 1.0f;
    out[loff + (size_t)n*K + tk0 + col] = f2bf(tile[col][row]*s);
  }
}

// ------------- split qkv + rope (bf16 in/out) --------------------------------
__global__ __launch_bounds__(256) void rope_apply_bf(const unsigned short* __restrict__ qkv,
    const float* __restrict__ sint, const float* __restrict__ cost,
    unsigned short* __restrict__ q, unsigned short* __restrict__ k,
    unsigned short* __restrict__ v){
  int row = blockIdx.x;                 // b*1024 + i
  int b = row>>10, i = row&1023;
  int tid = threadIdx.x; int h = tid>>5, d = tid&31;
  const unsigned short* base = qkv + (size_t)row*768;
  size_t oidx = (((size_t)((b<<3)+h)<<10) + i)*32 + d;
  v[oidx] = base[512 + h*32 + d];
  int dd = (d<16) ? d : d-16;
  float s = sint[i*16+dd], c = cost[i*16+dd];
  float q1 = bf2f(base[h*32+dd]), q2 = bf2f(base[h*32+dd+16]);
  q[oidx] = f2bf((d<16) ? (q1*c - q2*s) : (q2*c + q1*s));
  float k1 = bf2f(base[256+h*32+dd]), k2 = bf2f(base[256+h*32+dd+16]);
  k[oidx] = f2bf((d<16) ? (k1*c - k2*s) : (k2*c + k1*s));
}

// ------------- rel precompute: per-node separable parts + W2T ----------------
// blocks 0..511: A[node][64] (=b1+bv), A2[node][64] (=bv). block 512: W2T[16][64]
__global__ __launch_bounds__(256) void rel_pre(const float* __restrict__ coords,
    const float* __restrict__ vel, const float* __restrict__ W1,
    const float* __restrict__ b1, const float* __restrict__ W2,
    float* __restrict__ A, float* __restrict__ A2, unsigned short* __restrict__ W2T){
  if (blockIdx.x == 512){
    int t = threadIdx.x;
    #pragma unroll
    for (int e=0;e<4;++e){
      int idx = t*4+e;              // n*64 + k
      int n = idx>>6, kk = idx&63;
      W2T[idx] = (n<8) ? f2bf(W2[kk*8+n]) : 0;
    }
    return;
  }
  int gid = blockIdx.x*256 + threadIdx.x;  // 2048*64
  int node = gid >> 6, r = gid & 63;
  float c0 = coords[node*2], c1 = coords[node*2+1];
  float v0 = vel[node*2],    v1 = vel[node*2+1];
  float bv = c0*W1[r] + c1*W1[64+r] + v0*W1[192+r] + v1*W1[256+r];
  A[gid] = b1[r] + bv;
  A2[gid] = bv;
}

// ------------- rel fused v2: per-wave independent, no barriers ---------------
// wave w of block (b,i) handles j in [w*256, w*256+256), 64 at a time:
// gelu-poly(t) -> G (8KB private LDS, XOR-swizzled) -> MFMA @ W2T -> global bf16
__global__ __launch_bounds__(256) void rel_fused2(const float* __restrict__ coords,
    const float* __restrict__ A, const float* __restrict__ A2,
    const float* __restrict__ W1, const unsigned short* __restrict__ W2T,
    const float* __restrict__ b2, unsigned short* __restrict__ relbf){
  __shared__ __align__(16) unsigned short G[4][64*64];   // 32 KB, 8KB per wave
  const int tid = threadIdx.x;
  const int nodei = blockIdx.x;
  const int b = nodei >> 10, i = nodei & 1023;
  const int w = tid>>6, l = tid&63, lc = l&15, lg = l>>4;
  const float* Ai = A + (size_t)nodei*64;      // block-uniform -> s_load
  const float* Wd = W1 + 128;                  // uniform
  float ci0 = coords[nodei*2], ci1 = coords[nodei*2+1];
  // B-fragment of W2 (n=lc -> h, k=lg*8+e -> r)
  s16x8 bf0 = *(const s16x8*)&W2T[lc*64 + lg*8];
  s16x8 bf1 = *(const s16x8*)&W2T[lc*64 + 32 + lg*8];
  float b2v = (lc<8) ? b2[lc] : 0.f;
  unsigned short* Gw = G[w];
  size_t obase = ((size_t)b<<23) + ((size_t)i<<10);   // + (h<<20) + j

  for (int jt=0; jt<4; ++jt){
    int j0 = w*256 + jt*64;
    int j  = j0 + l;
    int nodej = (b<<10) + j;
    float2 cj = *(const float2*)(coords + (size_t)nodej*2);
    float dx = ci0-cj.x, dy = ci1-cj.y;
    float d = sqrtf(dx*dx+dy*dy);
    const float4* a2j = (const float4*)(A2 + (size_t)nodej*64);
    const int sw = l & 7;
    #pragma unroll
    for (int rg=0; rg<8; ++rg){
      float4 u0 = a2j[rg*2], u1 = a2j[rg*2+1];
      float tv[8] = {u0.x,u0.y,u0.z,u0.w,u1.x,u1.y,u1.z,u1.w};
      s16x8 pk;
      #pragma unroll
      for (int e=0; e<8; ++e){
        int r = rg*8+e;
        float t = fmaf(d, Wd[r], Ai[r] - tv[e]);
        float u = t*t;
        float p = fmaf(u, 0.0099735570f, -0.0664904395f);
        p = fmaf(u, p, 0.3989422804f);
        float g = fmaf(u, p, 0.5f*t);
        pk[e] = (short)f2bf(g);
      }
      // row stride 64 shorts = 128B; slot = rg ^ (l&7): 8 consecutive lanes
      // cover all 32 banks per b128 write
      *(s16x8*)&Gw[l*64 + ((rg ^ sw)<<3)] = pk;
    }
    // MFMA: 4 j-subtiles of 16; A-frag m=lc (row), k=lg*8+e; same XOR on read
    #pragma unroll
    for (int a=0;a<4;++a){
      int row = a*16 + lc;
      int rs = row & 7;
      s16x8 a0 = *(const s16x8*)&Gw[row*64 + ((lg ^ rs)<<3)];
      s16x8 a1 = *(const s16x8*)&Gw[row*64 + (((4+lg) ^ rs)<<3)];
      f32x4 z; z[0]=0.f; z[1]=0.f; z[2]=0.f; z[3]=0.f;
      z = mfma16(a0, bf0, z);
      z = mfma16(a1, bf1, z);
      if (lc < 8){
        unsigned int p0 = pack_bf16(z[0]+b2v, z[1]+b2v);
        unsigned int p1 = pack_bf16(z[2]+b2v, z[3]+b2v);
        size_t addr = obase + ((size_t)lc<<20) + (unsigned)(j0 + a*16 + lg*4);
        *(unsigned int*)&relbf[addr]   = p0;
        *(unsigned int*)&relbf[addr+2] = p1;
      }
    }
  }
}

// ------------- MFMA flash attention (all-bf16 inputs) -------------------------
__global__ __launch_bounds__(256) void attn_mfma(
    const unsigned short* __restrict__ q, const unsigned short* __restrict__ kk,
    const unsigned short* __restrict__ vv, const unsigned short* __restrict__ relbf,
    unsigned short* __restrict__ out){
  int bh = blockIdx.x >> 5;
  int i0 = (blockIdx.x & 31) * 32;
  int tid = threadIdx.x;
  int w  = tid >> 6;
  int l  = tid & 63;
  int lc = l & 15;
  int lg = l >> 4;

  __shared__ __align__(16) unsigned short VT[2][32*LPAD];
  __shared__ __align__(16) unsigned short PL[2][32*LPAD];
  __shared__ __align__(16) float wmaxs[2][32][4];
  __shared__ __align__(16) float wsums[2][32][4];
  __shared__ float mld[2][32];
  __shared__ float lld[2][32];

  const unsigned short* qb = q + ((size_t)(bh<<10) + i0)*32;
  const unsigned short* kb = kk + ((size_t)bh<<15);
  const unsigned short* vb = vv + ((size_t)bh<<15);
  const unsigned short* relb = relbf + ((size_t)bh<<20) + ((size_t)i0<<10);

  s16x8 qf0 = *(const s16x8*)(qb + (size_t)lc*32 + lg*8);
  s16x8 qf1 = *(const s16x8*)(qb + (size_t)(16+lc)*32 + lg*8);

  if (tid < 32){ mld[0][tid] = -1e30f; lld[0][tid] = 0.f; }

  f32x4 acc; acc[0]=0.f; acc[1]=0.f; acc[2]=0.f; acc[3]=0.f;
  const int dh  = w & 1;
  const int pih = w >> 1;

  for (int t=0; t<16; ++t){
    const int c = t & 1, nx = c ^ 1;
    const int j0 = t*64;
    {
      int jj = tid & 63, d0 = (tid >> 6)*8;
      s16x8 v8 = *(const s16x8*)(vb + (size_t)(j0+jj)*32 + d0);
      unsigned short* dst = VT[c];
      #pragma unroll
      for (int e=0;e<8;++e) dst[(d0+e)*LPAD + jj] = (unsigned short)v8[e];
    }
    s16x8 kf = *(const s16x8*)(kb + (size_t)(j0 + w*16 + lc)*32 + lg*8);
    f32x4 z; z[0]=0.f; z[1]=0.f; z[2]=0.f; z[3]=0.f;
    f32x4 s0 = mfma16(qf0, kf, z);
    f32x4 s1 = mfma16(qf1, kf, z);
    float sv0[4], sv1[4], rm0[4], rm1[4];
    const int jc = j0 + w*16 + lc;
    #pragma unroll
    for (int r=0;r<4;++r){
      int row0 = lg*4 + r;
      sv0[r] = s0[r] + bf2f(relb[(size_t)row0*1024 + jc]);
      sv1[r] = s1[r] + bf2f(relb[(size_t)(row0+16)*1024 + jc]);
      float a0 = sv0[r], a1 = sv1[r];
      #pragma unroll
      for (int o=1;o<16;o<<=1){
        a0 = fmaxf(a0, __shfl_xor(a0,o));
        a1 = fmaxf(a1, __shfl_xor(a1,o));
      }
      rm0[r]=a0; rm1[r]=a1;
    }
    if (lc == 0){
      #pragma unroll
      for (int r=0;r<4;++r){
        wmaxs[c][lg*4+r][w]    = rm0[r];
        wmaxs[c][lg*4+r+16][w] = rm1[r];
      }
    }
    __syncthreads();
    float mn0[4], mn1[4], sc0[4], sc1[4];
    #pragma unroll
    for (int r=0;r<4;++r){
      int row0 = lg*4+r;
      float4 wm0 = *(const float4*)wmaxs[c][row0];
      float4 wm1 = *(const float4*)wmaxs[c][row0+16];
      float mo0 = mld[c][row0], mo1 = mld[c][row0+16];
      float t0 = fmaxf(fmaxf(wm0.x,wm0.y), fmaxf(wm0.z,wm0.w));
      float t1 = fmaxf(fmaxf(wm1.x,wm1.y), fmaxf(wm1.z,wm1.w));
      mn0[r] = fmaxf(mo0, t0);  mn1[r] = fmaxf(mo1, t1);
      sc0[r] = __expf(mo0 - mn0[r]); sc1[r] = __expf(mo1 - mn1[r]);
    }
    float ps0[4], ps1[4];
    #pragma unroll
    for (int r=0;r<4;++r){
      int row0 = lg*4+r;
      float p0 = __expf(sv0[r]-mn0[r]);
      float p1 = __expf(sv1[r]-mn1[r]);
      PL[c][(size_t)row0*LPAD + w*16 + lc]      = f2bf(p0);
      PL[c][(size_t)(row0+16)*LPAD + w*16 + lc] = f2bf(p1);
      #pragma unroll
      for (int o=1;o<16;o<<=1){
        p0 += __shfl_xor(p0,o);
        p1 += __shfl_xor(p1,o);
      }
      ps0[r]=p0; ps1[r]=p1;
    }
    if (lc == 0){
      #pragma unroll
      for (int r=0;r<4;++r){
        wsums[c][lg*4+r][w]    = ps0[r];
        wsums[c][lg*4+r+16][w] = ps1[r];
      }
    }
    #pragma unroll
    for (int r=0;r<4;++r){
      float s = (pih==0) ? sc0[r] : sc1[r];
      acc[r] *= s;
    }
    __syncthreads();
    #pragma unroll
    for (int kc=0;kc<2;++kc){
      s16x8 pa = *(const s16x8*)&PL[c][(size_t)(pih*16 + lc)*LPAD + kc*32 + lg*8];
      s16x8 vf = *(const s16x8*)&VT[c][(size_t)(dh*16 + lc)*LPAD + kc*32 + lg*8];
      acc = mfma16(pa, vf, acc);
    }
    if (w==0 && lc==0){
      #pragma unroll
      for (int r=0;r<4;++r){
        int row0 = lg*4+r;
        float4 u0 = *(const float4*)wsums[c][row0];
        float4 u1 = *(const float4*)wsums[c][row0+16];
        lld[nx][row0]    = lld[c][row0]*sc0[r]    + (u0.x+u0.y+u0.z+u0.w);
        lld[nx][row0+16] = lld[c][row0+16]*sc1[r] + (u1.x+u1.y+u1.z+u1.w);
        mld[nx][row0]    = mn0[r];
        mld[nx][row0+16] = mn1[r];
      }
    }
  }
  __syncthreads();
  int b = bh>>3, hh = bh&7;
  #pragma unroll
  for (int r=0;r<4;++r){
    int row = pih*16 + lg*4 + r;
    float li = lld[0][row];
    out[((size_t)((b<<10)+i0+row))*256 + hh*32 + dh*16 + lc] = f2bf(acc[r]/li);
  }
}

// ------------- MFMA GEMM: C[M,NC] = A[M,K] @ W[K,NC], A bf16, WT bf16(NC,K) --
template<int K, int NC, int EPI, int BM, int BNt>
__global__ __launch_bounds__(256) void gemm_mfma(
    const unsigned short* __restrict__ Aa, const unsigned short* __restrict__ WT,
    const float* __restrict__ bias, const float* __restrict__ resid,
    void* __restrict__ outv){
  constexpr int WMm = BM/2, WNn = BNt/2;
  constexpr int FM = WMm/16, FN = WNn/16;
  constexpr int LP = 40;
  __shared__ __align__(16) unsigned short As[BM*LP];
  __shared__ __align__(16) unsigned short Bs[BNt*LP];
  const int tid = threadIdx.x;
  const int w = tid>>6, l = tid&63, lc = l&15, lg = l>>4;
  const int wm = w&1, wn = w>>1;
  const int n0 = blockIdx.x*BNt, m0 = blockIdx.y*BM;
  f32x4 acc[FM][FN];
  #pragma unroll
  for (int a=0;a<FM;++a)
    #pragma unroll
    for (int c=0;c<FN;++c){ acc[a][c][0]=0.f; acc[a][c][1]=0.f; acc[a][c][2]=0.f; acc[a][c][3]=0.f; }

  for (int k0=0; k0<K; k0+=32){
    __syncthreads();
    if constexpr (BM==64){
      int row = tid>>2, cg = tid&3;
      *(s16x8*)&As[row*LP+cg*8] = *(const s16x8*)&Aa[(size_t)(m0+row)*K + k0 + cg*8];
    } else {
      int row = tid>>3, cg = tid&7;
      *(ushort4*)&As[row*LP+cg*4] = *(const ushort4*)&Aa[(size_t)(m0+row)*K + k0 + cg*4];
    }
    if constexpr (BNt==64){
      int row = tid>>2, cg = tid&3;
      *(s16x8*)&Bs[row*LP+cg*8] = *(const s16x8*)&WT[(size_t)(n0+row)*K + k0 + cg*8];
    } else {
      int row = tid>>3, cg = tid&7;
      *(ushort4*)&Bs[row*LP+cg*4] = *(const ushort4*)&WT[(size_t)(n0+row)*K + k0 + cg*4];
    }
    __syncthreads();
    s16x8 af[FM], bv[FN];
    #pragma unroll
    for (int a=0;a<FM;++a) af[a] = *(const s16x8*)&As[(wm*WMm + a*16 + lc)*LP + lg*8];
    #pragma unroll
    for (int c=0;c<FN;++c) bv[c] = *(const s16x8*)&Bs[(wn*WNn + c*16 + lc)*LP + lg*8];
    #pragma unroll
    for (int a=0;a<FM;++a)
      #pragma unroll
      for (int c=0;c<FN;++c) acc[a][c] = mfma16(af[a], bv[c], acc[a][c]);
  }
  #pragma unroll
  for (int a=0;a<FM;++a){
    #pragma unroll
    for (int c=0;c<FN;++c){
      int n = n0 + wn*WNn + c*16 + lc;
      float bvv = (EPI!=0) ? bias[n] : 0.f;
      #pragma unroll
      for (int r=0;r<4;++r){
        int m = m0 + wm*WMm + a*16 + lg*4 + r;
        float vv = acc[a][c][r];
        if constexpr (EPI==0){
          ((unsigned short*)outv)[(size_t)m*NC + n] = f2bf(vv);
        } else if constexpr (EPI==1){
          ((float*)outv)[(size_t)m*NC + n] = vv + bvv + resid[(size_t)m*NC + n];
        } else {
          ((unsigned short*)outv)[(size_t)m*NC + n] = f2bf(gelu_f(vv + bvv));
        }
      }
    }
  }
}

extern "C" void kernel_launch(void* const* d_in, const int* in_sizes, int n_in,
                              void* d_out, int out_size, void* d_ws, size_t ws_size,
                              hipStream_t stream){
  const float* x_in  = (const float*)d_in[0];
  const float* coords= (const float*)d_in[1];
  const float* vel   = (const float*)d_in[2];
  const float* ln1_g = (const float*)d_in[3];
  const float* ln1_b = (const float*)d_in[4];
  const float* Wqkv  = (const float*)d_in[5];
  const float* relW1 = (const float*)d_in[6];
  const float* relb1 = (const float*)d_in[7];
  const float* relW2 = (const float*)d_in[8];
  const float* relb2 = (const float*)d_in[9];
  const float* Wout  = (const float*)d_in[10];
  const float* bout  = (const float*)d_in[11];
  const float* ln2_g = (const float*)d_in[12];
  const float* ln2_b = (const float*)d_in[13];
  const float* Wf1   = (const float*)d_in[14];
  const float* bf1   = (const float*)d_in[15];
  const float* Wf2   = (const float*)d_in[16];
  const float* bf2   = (const float*)d_in[17];

  float* x = (float*)d_out;
  unsigned short* us = (unsigned short*)d_ws;
  unsigned short* hbf   = us;                    // 524288
  unsigned short* qkvbf = hbf   + 524288;        // 1572864
  unsigned short* qbf   = qkvbf + 1572864;       // 524288
  unsigned short* kbf   = qbf   + 524288;        // 524288
  unsigned short* vbf   = kbf   + 524288;        // 524288
  unsigned short* attbf = vbf   + 524288;        // 524288
  unsigned short* midbf = attbf + 524288;        // 2097152
  unsigned short* relbf = midbf + 2097152;       // 16777216
  unsigned short* WqkvT = relbf + 16777216;      // 393216
  unsigned short* WoutT = WqkvT + 393216;        // 131072
  unsigned short* Wf1T  = WoutT + 131072;        // 524288
  unsigned short* Wf2T  = Wf1T  + 524288;        // 524288
  unsigned short* W2Tbf = Wf2T  + 524288;        // 1024
  float* Arel  = (float*)(W2Tbf + 1024);         // 131072
  float* A2rel = Arel + 131072;                  // 131072
  float* sint  = A2rel + 131072;                 // 16384
  float* cost  = sint + 16384;                   // 16384

  hipMemcpyAsync(x, x_in, sizeof(float)*524288, hipMemcpyDeviceToDevice, stream);
  rope_table<<<64,256,0,stream>>>(sint,cost);
  wt_convert<<<dim3(24,8,2),256,0,stream>>>(Wqkv, WqkvT, 256, 768, 256, SCALEV);
  wt_convert<<<dim3(8,8,2),256,0,stream>>>(Wout, WoutT, 256, 256, 0, 1.0f);
  wt_convert<<<dim3(32,8,2),256,0,stream>>>(Wf1, Wf1T, 256, 1024, 0, 1.0f);
  wt_convert<<<dim3(8,32,2),256,0,stream>>>(Wf2, Wf2T, 1024, 256, 0, 1.0f);

  for (int l=0;l<2;++l){
    ln_kernel<<<2048,256,0,stream>>>(x, ln1_g+l*256, ln1_b+l*256, hbf);
    gemm_mfma<256,768,0,64,64><<<dim3(12,32),256,0,stream>>>(
        hbf, WqkvT + (size_t)l*196608, nullptr, nullptr, qkvbf);
    rope_apply_bf<<<2048,256,0,stream>>>(qkvbf, sint, cost, qbf, kbf, vbf);
    rel_pre<<<513,256,0,stream>>>(coords, vel, relW1+l*320, relb1+l*64,
                                  relW2+l*512, Arel, A2rel, W2Tbf);
    rel_fused2<<<2048,256,0,stream>>>(coords, Arel, A2rel, relW1+l*320,
                                      W2Tbf, relb2+l*8, relbf);
    attn_mfma<<<512,256,0,stream>>>(qbf, kbf, vbf, relbf, attbf);
    gemm_mfma<256,256,1,64,32><<<dim3(8,32),256,0,stream>>>(
        attbf, WoutT + (size_t)l*65536, bout+l*256, x, x);
    ln_kernel<<<2048,256,0,stream>>>(x, ln2_g+l*256, ln2_b+l*256, hbf);
    gemm_mfma<256,1024,2,64,64><<<dim3(16,32),256,0,stream>>>(
        hbf, Wf1T + (size_t)l*262144, bf1+l*1024, nullptr, midbf);
    gemm_mfma<1024,256,1,64,32><<<dim3(8,32),256,0,stream>>>(
        midbf, Wf2T + (size_t)l*262144, bf2+l*256, x, x);
  }
}